// Round 3
// baseline (179.209 us; speedup 1.0000x reference)
//
#include <hip/hip_runtime.h>
#include <stdint.h>

typedef float  f32x4 __attribute__((ext_vector_type(4)));
typedef int    i32x4 __attribute__((ext_vector_type(4)));

// ---------------------------------------------------------------------------
// JAX threefry2x32 block cipher (20 rounds), bit-exact with jax._src.prng.
// Verified on-device R2: absmax = 0 vs jax.random.key(42) reference
// (partitionable threefry: split = cipher(key,(0,i)); bits = y0 ^ y1).
// ---------------------------------------------------------------------------
static __device__ __forceinline__ uint32_t rotl32(uint32_t x, int r) {
  return (x << r) | (x >> (32 - r));
}

static __device__ __forceinline__ void threefry2x32(uint32_t k0, uint32_t k1,
                                                    uint32_t& x0, uint32_t& x1) {
  const uint32_t ks0 = k0, ks1 = k1, ks2 = k0 ^ k1 ^ 0x1BD11BDAu;
  x0 += ks0; x1 += ks1;
#define TF4(a, b, c, d)                          \
  x0 += x1; x1 = rotl32(x1, (a)); x1 ^= x0;      \
  x0 += x1; x1 = rotl32(x1, (b)); x1 ^= x0;      \
  x0 += x1; x1 = rotl32(x1, (c)); x1 ^= x0;      \
  x0 += x1; x1 = rotl32(x1, (d)); x1 ^= x0;
  TF4(13, 15, 26, 6)   x0 += ks1; x1 += ks2 + 1u;
  TF4(17, 29, 16, 24)  x0 += ks2; x1 += ks0 + 2u;
  TF4(13, 15, 26, 6)   x0 += ks0; x1 += ks1 + 3u;
  TF4(17, 29, 16, 24)  x0 += ks1; x1 += ks2 + 4u;
  TF4(13, 15, 26, 6)   x0 += ks2; x1 += ks0 + 5u;
#undef TF4
}

static __device__ __forceinline__ float bits_to_unit_float(uint32_t bits) {
  return __uint_as_float((bits >> 9) | 0x3f800000u) - 1.0f;  // [0,1)
}

// ---------------------------------------------------------------------------
// Kernel 1: packed per-timestep delta bytes, delta[t] = idx[t]-t in {-1,0,+1}.
// Boundary: t==0 never -1, t==T-1 never +1 (so row-edge neighbor values are
// never selected by kernel 2, only speculatively loaded with clamped addr).
// ---------------------------------------------------------------------------
__global__ void jitter_delta_kernel(signed char* __restrict__ delta, int T) {
  int t = blockIdx.x * blockDim.x + threadIdx.x;
  if (t >= T) return;

  uint32_t kr0 = 0u, kr1 = 0u; threefry2x32(0u, 42u, kr0, kr1);  // k_rep
  uint32_t kd0 = 0u, kd1 = 1u; threefry2x32(0u, 42u, kd0, kd1);  // k_dir

  uint32_t a0 = 0u, a1 = (uint32_t)t; threefry2x32(kr0, kr1, a0, a1);
  uint32_t b0 = 0u, b1 = (uint32_t)t; threefry2x32(kd0, kd1, b0, b1);

  const bool replace = bits_to_unit_float(a0 ^ a1) < 0.12f;    // P_JITTER
  int dir = (bits_to_unit_float(b0 ^ b1) < 0.5f) ? 1 : -1;
  if (t == 0)     dir = 1;
  if (t == T - 1) dir = -1;

  delta[t] = replace ? (signed char)dir : (signed char)0;
}

// ---------------------------------------------------------------------------
// Kernel 2: out[row, t] = in[row, t + delta[t]]. 16 floats per thread:
//   1x dwordx4 delta load, 4x dwordx4 input, 2 edge scalars, 4 nt stores
//   (11 VMEM per 64B out, vs 24 in the scalar-gather version).
// Selection is 2 cndmasks per element from an 18-value register window.
// T = 8192 hardcoded (shifts); rows runtime.
// ---------------------------------------------------------------------------
__global__ void __launch_bounds__(256) jitter_gather16_kernel(
    const float* __restrict__ in, const signed char* __restrict__ delta,
    float* __restrict__ out, int total /* rows * 512 */) {
  int i = blockIdx.x * blockDim.x + threadIdx.x;
  const int stride = gridDim.x * blockDim.x;
  for (; i < total; i += stride) {
    const int row = i >> 9;              // 512 thread-tiles per row (8192/16)
    const int t0  = (i & 511) << 4;      // 16-float aligned tile start
    const long long base = (long long)row << 13;  // row * 8192
    const float* __restrict__ rin  = in  + base;
    float*       __restrict__ rout = out + base + t0;

    const i32x4 dv = *reinterpret_cast<const i32x4*>(delta + t0);  // 16 bytes

    const f32x4 va = *reinterpret_cast<const f32x4*>(rin + t0);
    const f32x4 vb = *reinterpret_cast<const f32x4*>(rin + t0 + 4);
    const f32x4 vc = *reinterpret_cast<const f32x4*>(rin + t0 + 8);
    const f32x4 vd = *reinterpret_cast<const f32x4*>(rin + t0 + 12);

    // 18-value window w[0..17] = [left, v0..v15, right]; all const-indexed.
    float w[18];
    w[0]  = rin[t0 ? t0 - 1 : 0];                    // clamped, never selected at t0==0
    w[1]  = va.x; w[2]  = va.y; w[3]  = va.z; w[4]  = va.w;
    w[5]  = vb.x; w[6]  = vb.y; w[7]  = vb.z; w[8]  = vb.w;
    w[9]  = vc.x; w[10] = vc.y; w[11] = vc.z; w[12] = vc.w;
    w[13] = vd.x; w[14] = vd.y; w[15] = vd.z; w[16] = vd.w;
    w[17] = rin[(t0 + 16 < 8192) ? t0 + 16 : 8191];  // clamped, never selected at end

    float ow[16];
#pragma unroll
    for (int j = 0; j < 16; ++j) {
      const uint32_t bb = (((uint32_t)dv[j >> 2]) >> ((j & 3) * 8)) & 0xffu;
      // bb: 0 -> keep, 1 -> next, 0xff -> prev
      ow[j] = (bb == 0u) ? w[j + 1] : ((bb == 1u) ? w[j + 2] : w[j]);
    }

#pragma unroll
    for (int q = 0; q < 4; ++q) {
      f32x4 o;
      o.x = ow[4 * q + 0]; o.y = ow[4 * q + 1];
      o.z = ow[4 * q + 2]; o.w = ow[4 * q + 3];
      __builtin_nontemporal_store(o, reinterpret_cast<f32x4*>(rout + 4 * q));
    }
  }
}

extern "C" void kernel_launch(void* const* d_in, const int* in_sizes, int n_in,
                              void* d_out, int out_size, void* d_ws, size_t ws_size,
                              hipStream_t stream) {
  const float* in = (const float*)d_in[0];
  float* out = (float*)d_out;
  signed char* delta = (signed char*)d_ws;   // 8192 B scratch

  const int T = 8192;
  const int rows = in_sizes[0] / T;          // 32 * 256 = 8192
  const int total = rows * (T / 16);         // 4,194,304 thread-tiles

  jitter_delta_kernel<<<(T + 255) / 256, 256, 0, stream>>>(delta, T);
  jitter_gather16_kernel<<<4096, 256, 0, stream>>>(in, delta, out, total);
}

// Round 4
// 93.344 us; speedup vs baseline: 1.9199x; 1.9199x over previous
//
#include <hip/hip_runtime.h>
#include <stdint.h>

typedef float  f32x4 __attribute__((ext_vector_type(4)));

// ---------------------------------------------------------------------------
// JAX threefry2x32 block cipher (20 rounds), bit-exact with jax._src.prng.
// Verified on-device R2: absmax = 0 vs jax.random.key(42) reference
// (partitionable threefry: split = cipher(key,(0,i)); bits = y0 ^ y1).
// ---------------------------------------------------------------------------
static __device__ __forceinline__ uint32_t rotl32(uint32_t x, int r) {
  return (x << r) | (x >> (32 - r));
}

static __device__ __forceinline__ void threefry2x32(uint32_t k0, uint32_t k1,
                                                    uint32_t& x0, uint32_t& x1) {
  const uint32_t ks0 = k0, ks1 = k1, ks2 = k0 ^ k1 ^ 0x1BD11BDAu;
  x0 += ks0; x1 += ks1;
#define TF4(a, b, c, d)                          \
  x0 += x1; x1 = rotl32(x1, (a)); x1 ^= x0;      \
  x0 += x1; x1 = rotl32(x1, (b)); x1 ^= x0;      \
  x0 += x1; x1 = rotl32(x1, (c)); x1 ^= x0;      \
  x0 += x1; x1 = rotl32(x1, (d)); x1 ^= x0;
  TF4(13, 15, 26, 6)   x0 += ks1; x1 += ks2 + 1u;
  TF4(17, 29, 16, 24)  x0 += ks2; x1 += ks0 + 2u;
  TF4(13, 15, 26, 6)   x0 += ks0; x1 += ks1 + 3u;
  TF4(17, 29, 16, 24)  x0 += ks1; x1 += ks2 + 4u;
  TF4(13, 15, 26, 6)   x0 += ks2; x1 += ks0 + 5u;
#undef TF4
}

static __device__ __forceinline__ float bits_to_unit_float(uint32_t bits) {
  return __uint_as_float((bits >> 9) | 0x3f800000u) - 1.0f;  // [0,1)
}

// ---------------------------------------------------------------------------
// Kernel 1: packed per-timestep delta bytes, delta[t] = idx[t]-t in {-1,0,+1}.
// Boundary: delta[0] != -1 and delta[T-1] != +1, so clamped edge values in
// kernel 2 are never selected.
// ---------------------------------------------------------------------------
__global__ void jitter_delta_kernel(signed char* __restrict__ delta, int T) {
  int t = blockIdx.x * blockDim.x + threadIdx.x;
  if (t >= T) return;

  uint32_t kr0 = 0u, kr1 = 0u; threefry2x32(0u, 42u, kr0, kr1);  // k_rep
  uint32_t kd0 = 0u, kd1 = 1u; threefry2x32(0u, 42u, kd0, kd1);  // k_dir

  uint32_t a0 = 0u, a1 = (uint32_t)t; threefry2x32(kr0, kr1, a0, a1);
  uint32_t b0 = 0u, b1 = (uint32_t)t; threefry2x32(kd0, kd1, b0, b1);

  const bool replace = bits_to_unit_float(a0 ^ a1) < 0.12f;    // P_JITTER
  int dir = (bits_to_unit_float(b0 ^ b1) < 0.5f) ? 1 : -1;
  if (t == 0)     dir = 1;
  if (t == T - 1) dir = -1;

  delta[t] = replace ? (signed char)dir : (signed char)0;
}

// ---------------------------------------------------------------------------
// Kernel 2: out[row, t] = in[row, t + delta[t]].
// Layout: 4 floats per lane (16 B lane stride -> fully coalesced f32x4 ops),
// 4 rows per thread (independent chains, delta dword amortized 4x).
// Neighbors come from the wave via shfl; only lanes 0/63 do a 1-line
// exec-masked edge load (clamped, never selected at row boundaries).
// ---------------------------------------------------------------------------
__global__ void __launch_bounds__(256) jitter_gather4x4_kernel(
    const float* __restrict__ in, const signed char* __restrict__ delta,
    float* __restrict__ out, int totalThreads /* (rows/4) * 2048 */,
    int quarterRows /* rows/4 */) {
  const int lane = threadIdx.x & 63;
  int i = blockIdx.x * blockDim.x + threadIdx.x;
  const int stride = gridDim.x * blockDim.x;

  for (; i < totalThreads; i += stride) {
    const int row0 = i >> 11;            // 2048 threads per row
    const int t0   = (i & 2047) << 2;    // 4-float tile start

    const long long b0 = ((long long)row0) << 13;                      // row0*8192
    const long long b1 = ((long long)(row0 + quarterRows)) << 13;
    const long long b2 = ((long long)(row0 + 2 * quarterRows)) << 13;
    const long long b3 = ((long long)(row0 + 3 * quarterRows)) << 13;

    // main vector loads (4 independent chains)
    const f32x4 v0 = *reinterpret_cast<const f32x4*>(in + b0 + t0);
    const f32x4 v1 = *reinterpret_cast<const f32x4*>(in + b1 + t0);
    const f32x4 v2 = *reinterpret_cast<const f32x4*>(in + b2 + t0);
    const f32x4 v3 = *reinterpret_cast<const f32x4*>(in + b3 + t0);

    // shared delta dword (coalesced 256 B per wave)
    const uint32_t db = *reinterpret_cast<const uint32_t*>(delta + t0);

    // neighbor edges via cross-lane shuffle
    float l0 = __shfl_up(v0.w, 1), r0 = __shfl_down(v0.x, 1);
    float l1 = __shfl_up(v1.w, 1), r1 = __shfl_down(v1.x, 1);
    float l2 = __shfl_up(v2.w, 1), r2 = __shfl_down(v2.x, 1);
    float l3 = __shfl_up(v3.w, 1), r3 = __shfl_down(v3.x, 1);

    // wave-edge lanes: 1-line exec-masked loads (clamped; never selected
    // at t==0 / t==T-1 because delta there excludes the offending dir)
    if (lane == 0) {
      const int tl = t0 ? t0 - 1 : 0;
      l0 = in[b0 + tl]; l1 = in[b1 + tl]; l2 = in[b2 + tl]; l3 = in[b3 + tl];
    }
    if (lane == 63) {
      const int tr = (t0 + 4 < 8192) ? t0 + 4 : 8191;
      r0 = in[b0 + tr]; r1 = in[b1 + tr]; r2 = in[b2 + tr]; r3 = in[b3 + tr];
    }

    const uint32_t d0 = db & 0xffu;
    const uint32_t d1 = (db >> 8) & 0xffu;
    const uint32_t d2 = (db >> 16) & 0xffu;
    const uint32_t d3 = db >> 24;

#define SEL(v, lft, rgt, o)                                            \
    o.x = (d0 == 0u) ? v.x : ((d0 == 1u) ? v.y : lft);                 \
    o.y = (d1 == 0u) ? v.y : ((d1 == 1u) ? v.z : v.x);                 \
    o.z = (d2 == 0u) ? v.z : ((d2 == 1u) ? v.w : v.y);                 \
    o.w = (d3 == 0u) ? v.w : ((d3 == 1u) ? rgt : v.z);

    f32x4 o0, o1, o2, o3;
    SEL(v0, l0, r0, o0)
    SEL(v1, l1, r1, o1)
    SEL(v2, l2, r2, o2)
    SEL(v3, l3, r3, o3)
#undef SEL

    __builtin_nontemporal_store(o0, reinterpret_cast<f32x4*>(out + b0 + t0));
    __builtin_nontemporal_store(o1, reinterpret_cast<f32x4*>(out + b1 + t0));
    __builtin_nontemporal_store(o2, reinterpret_cast<f32x4*>(out + b2 + t0));
    __builtin_nontemporal_store(o3, reinterpret_cast<f32x4*>(out + b3 + t0));
  }
}

extern "C" void kernel_launch(void* const* d_in, const int* in_sizes, int n_in,
                              void* d_out, int out_size, void* d_ws, size_t ws_size,
                              hipStream_t stream) {
  const float* in = (const float*)d_in[0];
  float* out = (float*)d_out;
  signed char* delta = (signed char*)d_ws;   // 8192 B scratch

  const int T = 8192;
  const int rows = in_sizes[0] / T;          // 32 * 256 = 8192
  const int quarterRows = rows >> 2;         // 2048
  const int totalThreads = quarterRows * (T / 4);  // 4,194,304

  jitter_delta_kernel<<<(T + 255) / 256, 256, 0, stream>>>(delta, T);
  jitter_gather4x4_kernel<<<4096, 256, 0, stream>>>(in, delta, out,
                                                    totalThreads, quarterRows);
}